// Round 5
// baseline (642.041 us; speedup 1.0000x reference)
//
#include <hip/hip_runtime.h>
#include <hip/hip_cooperative_groups.h>
#include <cstdint>
#include <cstddef>

namespace cg = cooperative_groups;

#define D 768
#define BATCH 8
#define LC 2048
#define LQ 1024
#define SCALE 0.03608439182435161f /* 1/sqrt(768) */

typedef __attribute__((ext_vector_type(8))) short short8;
typedef __attribute__((ext_vector_type(4))) float floatx4;

__device__ __forceinline__ short f2bf(float f) {
    union { float f; uint32_t u; } v; v.f = f;
    uint32_t r = v.u + 0x7fffu + ((v.u >> 16) & 1u);
    return (short)(r >> 16);
}

// ---- async global->LDS, 16B per lane ----
__device__ __forceinline__ void gl_lds16(const short* g, short* l) {
    __builtin_amdgcn_global_load_lds(
        reinterpret_cast<const __attribute__((address_space(1))) unsigned int*>(
            reinterpret_cast<uintptr_t>(g)),
        reinterpret_cast<__attribute__((address_space(3))) unsigned int*>(
            reinterpret_cast<uintptr_t>(l)),
        16, 0, 0);
}

// ================= 256x256 core: BK=32, 3 buffers, phase-locked counted-vmcnt =================
// (verbatim from the verified round-1/round-4 kernel; BUFSZ = 16384 shorts = 32 KiB)
__device__ __forceinline__ void gemm256_loop(
    const short* __restrict__ A, const short* __restrict__ B,
    int lda, int ldb, int K, int m0, int n0,
    short* lds, int tid, floatx4 acc[8][4]) {
    const int lane = tid & 63, l15 = lane & 15, quad = lane >> 4;
    const int w = tid >> 6, wm = w >> 2, wn = w & 3;

    const int c0 = tid, c1 = tid + 512;
    const int r0 = c0 >> 2, s0 = (c0 & 3) ^ (r0 & 3);
    const int r1 = c1 >> 2, s1 = (c1 & 3) ^ (r1 & 3);
    const short* gA0 = A + (size_t)(m0 + r0) * lda + s0 * 8;
    const short* gA1 = A + (size_t)(m0 + r1) * lda + s1 * 8;
    const short* gB0 = B + (size_t)(n0 + r0) * ldb + s0 * 8;
    const short* gB1 = B + (size_t)(n0 + r1) * ldb + s1 * 8;
    short* dA0 = lds + c0 * 8;
    short* dA1 = lds + c1 * 8;
    short* dB0 = lds + 8192 + c0 * 8;
    short* dB1 = lds + 8192 + c1 * 8;

    int aoff[8], boff[4];
#pragma unroll
    for (int mt = 0; mt < 8; ++mt) {
        int r = wm * 128 + mt * 16 + l15;
        aoff[mt] = r * 32 + ((quad ^ (r & 3)) * 8);
    }
#pragma unroll
    for (int nt = 0; nt < 4; ++nt) {
        int r = wn * 64 + nt * 16 + l15;
        boff[nt] = 8192 + r * 32 + ((quad ^ (r & 3)) * 8);
    }

    const int NT = K >> 5;
#define STAGE_A2(t, bb) { gl_lds16(gA0 + (t) * 32, dA0 + (bb)); gl_lds16(gA1 + (t) * 32, dA1 + (bb)); }
#define STAGE_B2(t, bb) { gl_lds16(gB0 + (t) * 32, dB0 + (bb)); gl_lds16(gB1 + (t) * 32, dB1 + (bb)); }
    STAGE_A2(0, 0) STAGE_B2(0, 0)
    STAGE_A2(1, 16384) STAGE_B2(1, 16384)

    for (int kt = 0; kt < NT; ++kt) {
        const int cur = (kt % 3) * 16384;
        const int nxt = ((kt + 2) % 3) * 16384;
        if (kt + 1 < NT) { asm volatile("s_waitcnt vmcnt(4)" ::: "memory"); }
        else             { asm volatile("s_waitcnt vmcnt(0)" ::: "memory"); }
        __builtin_amdgcn_s_barrier();

        if (kt + 2 < NT) STAGE_A2((kt + 2), nxt)
        short8 af0[4], bf[4];
#pragma unroll
        for (int mt = 0; mt < 4; ++mt)
            af0[mt] = *reinterpret_cast<const short8*>(lds + cur + aoff[mt]);
#pragma unroll
        for (int nt = 0; nt < 4; ++nt)
            bf[nt] = *reinterpret_cast<const short8*>(lds + cur + boff[nt]);
        asm volatile("s_waitcnt lgkmcnt(0)" ::: "memory");
        __builtin_amdgcn_s_setprio(1);
#pragma unroll
        for (int mt = 0; mt < 4; ++mt)
#pragma unroll
            for (int nt = 0; nt < 4; ++nt)
                acc[mt][nt] = __builtin_amdgcn_mfma_f32_16x16x32_bf16(af0[mt], bf[nt], acc[mt][nt], 0, 0, 0);
        __builtin_amdgcn_s_setprio(0);
        __builtin_amdgcn_s_barrier();

        if (kt + 2 < NT) STAGE_B2((kt + 2), nxt)
        short8 af1[4];
#pragma unroll
        for (int mt = 0; mt < 4; ++mt)
            af1[mt] = *reinterpret_cast<const short8*>(lds + cur + aoff[4 + mt]);
        asm volatile("s_waitcnt lgkmcnt(0)" ::: "memory");
        __builtin_amdgcn_s_setprio(1);
#pragma unroll
        for (int mt = 0; mt < 4; ++mt)
#pragma unroll
            for (int nt = 0; nt < 4; ++nt)
                acc[4 + mt][nt] = __builtin_amdgcn_mfma_f32_16x16x32_bf16(af1[mt], bf[nt], acc[4 + mt][nt], 0, 0, 0);
        __builtin_amdgcn_s_setprio(0);
    }
#undef STAGE_A2
#undef STAGE_B2
}

// ================= 256x128 core: same schedule, BN=128 (for gemm1) =================
// BUFSZ = 12288 shorts = 24 KiB (A 256x32 @0, B 128x32 @8192). 3 loads/thread/tile -> gate vmcnt(3).
__device__ __forceinline__ void gemm256x128_loop(
    const short* __restrict__ A, const short* __restrict__ B,
    int lda, int ldb, int K, int m0, int n0,
    short* lds, int tid, floatx4 acc[8][2]) {
    const int lane = tid & 63, l15 = lane & 15, quad = lane >> 4;
    const int w = tid >> 6, wm = w >> 2, wn = w & 3;

    const int c0 = tid, c1 = tid + 512;
    const int r0 = c0 >> 2, s0 = (c0 & 3) ^ (r0 & 3);
    const int r1 = c1 >> 2, s1 = (c1 & 3) ^ (r1 & 3);
    const int rB = tid >> 2, sB = (tid & 3) ^ (rB & 3);
    const short* gA0 = A + (size_t)(m0 + r0) * lda + s0 * 8;
    const short* gA1 = A + (size_t)(m0 + r1) * lda + s1 * 8;
    const short* gB0 = B + (size_t)(n0 + rB) * ldb + sB * 8;
    short* dA0 = lds + c0 * 8;
    short* dA1 = lds + c1 * 8;
    short* dB0 = lds + 8192 + tid * 8;

    int aoff[8], boff[2];
#pragma unroll
    for (int mt = 0; mt < 8; ++mt) {
        int r = wm * 128 + mt * 16 + l15;
        aoff[mt] = r * 32 + ((quad ^ (r & 3)) * 8);
    }
#pragma unroll
    for (int nt = 0; nt < 2; ++nt) {
        int r = wn * 32 + nt * 16 + l15;
        boff[nt] = 8192 + r * 32 + ((quad ^ (r & 3)) * 8);
    }

    const int NT = K >> 5;
#define STAGE_A1(t, bb) { gl_lds16(gA0 + (t) * 32, dA0 + (bb)); gl_lds16(gA1 + (t) * 32, dA1 + (bb)); }
#define STAGE_B1(t, bb) { gl_lds16(gB0 + (t) * 32, dB0 + (bb)); }
    STAGE_A1(0, 0) STAGE_B1(0, 0)
    STAGE_A1(1, 12288) STAGE_B1(1, 12288)

    for (int kt = 0; kt < NT; ++kt) {
        const int cur = (kt % 3) * 12288;
        const int nxt = ((kt + 2) % 3) * 12288;
        if (kt + 1 < NT) { asm volatile("s_waitcnt vmcnt(3)" ::: "memory"); }
        else             { asm volatile("s_waitcnt vmcnt(0)" ::: "memory"); }
        __builtin_amdgcn_s_barrier();

        if (kt + 2 < NT) STAGE_A1((kt + 2), nxt)
        short8 af0[4], bf[2];
#pragma unroll
        for (int mt = 0; mt < 4; ++mt)
            af0[mt] = *reinterpret_cast<const short8*>(lds + cur + aoff[mt]);
#pragma unroll
        for (int nt = 0; nt < 2; ++nt)
            bf[nt] = *reinterpret_cast<const short8*>(lds + cur + boff[nt]);
        asm volatile("s_waitcnt lgkmcnt(0)" ::: "memory");
        __builtin_amdgcn_s_setprio(1);
#pragma unroll
        for (int mt = 0; mt < 4; ++mt)
#pragma unroll
            for (int nt = 0; nt < 2; ++nt)
                acc[mt][nt] = __builtin_amdgcn_mfma_f32_16x16x32_bf16(af0[mt], bf[nt], acc[mt][nt], 0, 0, 0);
        __builtin_amdgcn_s_setprio(0);
        __builtin_amdgcn_s_barrier();

        if (kt + 2 < NT) STAGE_B1((kt + 2), nxt)
        short8 af1[4];
#pragma unroll
        for (int mt = 0; mt < 4; ++mt)
            af1[mt] = *reinterpret_cast<const short8*>(lds + cur + aoff[4 + mt]);
        asm volatile("s_waitcnt lgkmcnt(0)" ::: "memory");
        __builtin_amdgcn_s_setprio(1);
#pragma unroll
        for (int mt = 0; mt < 4; ++mt)
#pragma unroll
            for (int nt = 0; nt < 2; ++nt)
                acc[4 + mt][nt] = __builtin_amdgcn_mfma_f32_16x16x32_bf16(af1[mt], bf[nt], acc[4 + mt][nt], 0, 0, 0);
        __builtin_amdgcn_s_setprio(0);
    }
#undef STAGE_A1
#undef STAGE_B1
}

// ================= cooperative mega-kernel: prep -> gemm1 -> scores -> gemm2 =================
__global__ __launch_bounds__(512, 2) void mega_kernel(
    const float* __restrict__ ctx, const float* __restrict__ qh,
    const int* __restrict__ qmask, const float* __restrict__ Wf,
    const float* __restrict__ bias, float* __restrict__ out,
    short* __restrict__ W_b, short* __restrict__ query_b, short* __restrict__ qhT,
    short* __restrict__ ctx_b, short* __restrict__ P, float* __restrict__ sums,
    short* __restrict__ qh_b) {
    __shared__ __align__(16) short lds[3 * 16384];  // 96 KiB, reused by every phase
    cg::grid_group grid = cg::this_grid();
    const int tid = threadIdx.x;
    const int bid = blockIdx.x;
    const int gid = bid * 512 + tid;
    const int nth = 256 * 512;

    // ---------------- phase 0: prep (cast W, zero sums, ctx copy+cast, qh cast+transpose) ----
    {
        // W: 768*768/4 = 147456 float4 items
        for (int i = gid; i < 147456; i += nth) {
            float4 v = reinterpret_cast<const float4*>(Wf)[i];
            short4 o;
            o.x = f2bf(v.x); o.y = f2bf(v.y); o.z = f2bf(v.z); o.w = f2bf(v.w);
            reinterpret_cast<short4*>(W_b)[i] = o;
        }
        // sums zero: 16384 floats = 4096 float4
        for (int i = gid; i < 4096; i += nth) {
            float4 z = {0.f, 0.f, 0.f, 0.f};
            reinterpret_cast<float4*>(sums)[i] = z;
        }
        // ctx: copy into out[:, :, 0:768] and cast to bf16. 8*2048*768/4 = 3145728 f4 items
        for (int i = gid; i < 3145728; i += nth) {
            int row = i / 192, c4 = i % 192;
            float4 v = reinterpret_cast<const float4*>(ctx)[i];
            reinterpret_cast<float4*>(out)[(size_t)row * 384 + c4] = v;
            short4 o;
            o.x = f2bf(v.x); o.y = f2bf(v.y); o.z = f2bf(v.z); o.w = f2bf(v.w);
            reinterpret_cast<short4*>(ctx_b)[i] = o;
        }
        // qh: 6144 tiles of 32x32; each block does 2 tiles/iter (tid>>8 selects sub-tile)
        float* tf = reinterpret_cast<float*>(lds);          // 2 * 32*33 floats = 8448 floats
        float* mytile = tf + (tid >> 8) * (32 * 33);
        const int st = tid & 255;
        const int r = st >> 3, c = (st & 7) * 4;
        for (int t2 = bid; t2 < 3072; t2 += 256) {
            const int T = t2 * 2 + (tid >> 8);
            const int b = T / 768, rem = T % 768;
            const int q0 = (rem / 24) * 32, d0 = (rem % 24) * 32;
            const float4 v = *reinterpret_cast<const float4*>(
                qh + ((size_t)b * LQ + q0 + r) * D + d0 + c);
            mytile[r * 33 + c] = v.x; mytile[r * 33 + c + 1] = v.y;
            mytile[r * 33 + c + 2] = v.z; mytile[r * 33 + c + 3] = v.w;
            short4 d;
            d.x = f2bf(v.x); d.y = f2bf(v.y); d.z = f2bf(v.z); d.w = f2bf(v.w);
            *reinterpret_cast<short4*>(qh_b + ((size_t)b * LQ + q0 + r) * D + d0 + c) = d;
            __syncthreads();
            short4 o;
            o.x = f2bf(mytile[(c + 0) * 33 + r]); o.y = f2bf(mytile[(c + 1) * 33 + r]);
            o.z = f2bf(mytile[(c + 2) * 33 + r]); o.w = f2bf(mytile[(c + 3) * 33 + r]);
            *reinterpret_cast<short4*>(qhT + ((size_t)b * D + d0 + r) * LQ + q0 + c) = o;
            __syncthreads();
        }
    }
    __threadfence();
    grid.sync();
    __threadfence();

    // ---------------- phase 1: gemm1 (query = qh_b * W^T + bias), 192 tiles of 256x128 ----
    if (bid < 192) {
        const int nb = (bid & 7) * 24 + (bid >> 3);   // XCD-grouped
        const int m0 = (nb / 6) * 256, n0 = (nb % 6) * 128;
        const int lane = tid & 63, l15 = lane & 15, quad = lane >> 4;
        const int w = tid >> 6, wm = w >> 2, wn = w & 3;
        floatx4 acc[8][2];
#pragma unroll
        for (int i = 0; i < 8; ++i)
#pragma unroll
            for (int j = 0; j < 2; ++j) { floatx4 z = {0.f, 0.f, 0.f, 0.f}; acc[i][j] = z; }
        gemm256x128_loop(qh_b, W_b, D, D, D, m0, n0, lds, tid, acc);
        float bv[2];
#pragma unroll
        for (int nt = 0; nt < 2; ++nt) bv[nt] = bias[n0 + wn * 32 + nt * 16 + l15];
#pragma unroll
        for (int mt = 0; mt < 8; ++mt)
#pragma unroll
            for (int rr = 0; rr < 4; ++rr) {
                int row = m0 + wm * 128 + mt * 16 + quad * 4 + rr;
#pragma unroll
                for (int nt = 0; nt < 2; ++nt)
                    query_b[(size_t)row * D + n0 + wn * 32 + nt * 16 + l15] =
                        f2bf(acc[mt][nt][rr] + bv[nt]);
            }
    }
    __threadfence();
    grid.sync();
    __threadfence();

    // ---------------- phase 2: scores (P_unnorm + row sums), 256 tiles of 256x256 ----------
    {
        const int nb = ((bid & 7) << 5) + (bid >> 3);   // one batch per XCD
        const int b = nb >> 5, rem = nb & 31, by = rem >> 3, bx = rem & 7;
        const int m0 = bx << 8, n0 = by << 8;
        const int lane = tid & 63, l15 = lane & 15, quad = lane >> 4;
        const int w = tid >> 6, wm = w >> 2, wn = w & 3;
        floatx4 acc[8][4];
#pragma unroll
        for (int i = 0; i < 8; ++i)
#pragma unroll
            for (int j = 0; j < 4; ++j) { floatx4 z = {0.f, 0.f, 0.f, 0.f}; acc[i][j] = z; }
        gemm256_loop(ctx_b + (size_t)b * LC * D, query_b + (size_t)b * LQ * D,
                     D, D, D, m0, n0, lds, tid, acc);
        const int* mk = qmask + b * LQ;
        bool valid[4];
#pragma unroll
        for (int nt = 0; nt < 4; ++nt) valid[nt] = (mk[n0 + wn * 64 + nt * 16 + l15] != 0);
        short* Pb = P + (size_t)b * LC * LQ;
        float* sumb = sums + (size_t)b * LC;
#pragma unroll
        for (int mt = 0; mt < 8; ++mt)
#pragma unroll
            for (int rr = 0; rr < 4; ++rr) {
                int row = m0 + wm * 128 + mt * 16 + quad * 4 + rr;
                float psum = 0.f;
#pragma unroll
                for (int nt = 0; nt < 4; ++nt) {
                    float pv = valid[nt] ? __expf(acc[mt][nt][rr] * SCALE) : 0.f;
                    psum += pv;
                    Pb[(size_t)row * LQ + n0 + wn * 64 + nt * 16 + l15] = f2bf(pv);
                }
#pragma unroll
                for (int off = 1; off < 16; off <<= 1)
                    psum += __shfl_xor(psum, off, 64);
                if (l15 == 0)
                    atomicAdd(&sumb[row], psum);
            }
    }
    __threadfence();
    grid.sync();
    __threadfence();

    // ---------------- phase 3: gemm2 (attn_out = P*qhT^T / rowsum), 192 tiles of 256x256 ----
    if (bid < 192) {
        const int nb = (bid & 7) * 24 + (bid >> 3);
        const int b = nb / 24, rem = nb % 24, by = rem >> 3, bx = rem & 7;
        const int m0 = bx << 8, n0 = by << 8;
        const int lane = tid & 63, l15 = lane & 15, quad = lane >> 4;
        const int w = tid >> 6, wm = w >> 2, wn = w & 3;
        floatx4 acc[8][4];
#pragma unroll
        for (int i = 0; i < 8; ++i)
#pragma unroll
            for (int j = 0; j < 4; ++j) { floatx4 z = {0.f, 0.f, 0.f, 0.f}; acc[i][j] = z; }
        gemm256_loop(P + (size_t)b * LC * LQ, qhT + (size_t)b * D * LQ,
                     LQ, LQ, LQ, m0, n0, lds, tid, acc);
        const float* sumb = sums + (size_t)b * LC;
#pragma unroll
        for (int mt = 0; mt < 8; ++mt)
#pragma unroll
            for (int rr = 0; rr < 4; ++rr) {
                int lrow = m0 + wm * 128 + mt * 16 + quad * 4 + rr;
                const float inv = 1.0f / sumb[lrow];
                size_t rowoff = ((size_t)b * LC + lrow) * 1536 + 768;
#pragma unroll
                for (int nt = 0; nt < 4; ++nt)
                    out[rowoff + n0 + wn * 64 + nt * 16 + l15] = acc[mt][nt][rr] * inv;
            }
    }
}

extern "C" void kernel_launch(void* const* d_in, const int* in_sizes, int n_in,
                              void* d_out, int out_size, void* d_ws, size_t ws_size,
                              hipStream_t stream) {
    const float* ctx = (const float*)d_in[0];
    const float* qh = (const float*)d_in[2];
    const int* qmask = (const int*)d_in[3];
    const float* Wf = (const float*)d_in[4];
    const float* bias = (const float*)d_in[5];
    float* out = (float*)d_out;

    char* ws = (char*)d_ws;
    short* W_b     = (short*)(ws);                  //  1,179,648 B
    short* query_b = (short*)(ws + 1179648);        // 12,582,912 B
    short* qhT     = (short*)(ws + 13762560);       // 12,582,912 B
    short* ctx_b   = (short*)(ws + 26345472);       // 25,165,824 B
    short* P       = (short*)(ws + 51511296);       // 33,554,432 B
    float* sums    = (float*)(ws + 85065728);       //     65,536 B -> end 85,131,264
    short* qh_b    = (short*)(ws + 51511296);       // alias with P (dead before scores writes P)

    void* args[] = {(void*)&ctx, (void*)&qh, (void*)&qmask, (void*)&Wf, (void*)&bias,
                    (void*)&out, (void*)&W_b, (void*)&query_b, (void*)&qhT, (void*)&ctx_b,
                    (void*)&P, (void*)&sums, (void*)&qh_b};
    hipLaunchCooperativeKernel(mega_kernel, dim3(256), dim3(512), args, 0, stream);
}

// Round 6
// 269.156 us; speedup vs baseline: 2.3854x; 2.3854x over previous
//
#include <hip/hip_runtime.h>
#include <hip/hip_bf16.h>
#include <cstdint>
#include <cstddef>

#define D 768
#define BATCH 8
#define LC 2048
#define LQ 1024
#define SCALE 0.03608439182435161f /* 1/sqrt(768) */

typedef __attribute__((ext_vector_type(8))) short short8;
typedef __attribute__((ext_vector_type(4))) float floatx4;

__device__ __forceinline__ short f2bf(float f) {
    union { float f; uint32_t u; } v; v.f = f;
    uint32_t r = v.u + 0x7fffu + ((v.u >> 16) & 1u);
    return (short)(r >> 16);
}

// ---- async global->LDS, 16B per lane ----
__device__ __forceinline__ void gl_lds16(const short* g, short* l) {
    __builtin_amdgcn_global_load_lds(
        reinterpret_cast<const __attribute__((address_space(1))) unsigned int*>(
            reinterpret_cast<uintptr_t>(g)),
        reinterpret_cast<__attribute__((address_space(3))) unsigned int*>(
            reinterpret_cast<uintptr_t>(l)),
        16, 0, 0);
}

// ================= 128x256 core: BK=32, 3 buffers, free-drift counted-vmcnt =================
// C[128,256] = A[128,K] * B[256,K]^T, row-major. 512 thr = 8 waves (2 wm x 4 wn),
// wave tile 64x64, acc[4][4]. LDS buffer = A 128x32 (4096 sh) + B 256x32 (8192 sh)
// = 12288 shorts (24 KiB); 3 buffers = 72 KiB -> 2 blocks/CU.
// 16B-slot involution swizzle slot^=(row&3) on BOTH stage source and ds_read (rule #21).
// 3 loads/thread/tile (A:1, B:2) -> steady-state gate vmcnt(3) (next tile in flight).
// Schedule = round-1 free-drift structure (best measured: 265.8 us).
__device__ __forceinline__ void gemm128x256_loop(
    const short* __restrict__ A, const short* __restrict__ B,
    int lda, int ldb, int K, int m0, int n0,
    short* lds, int tid, floatx4 acc[4][4]) {
    const int lane = tid & 63, l15 = lane & 15, quad = lane >> 4;
    const int w = tid >> 6, wm = w >> 2, wn = w & 3;

    // A: 512 chunks (128 rows x 4 slots), 1 per thread
    const int ra = tid >> 2, sa = (tid & 3) ^ (ra & 3);
    const short* gA = A + (size_t)(m0 + ra) * lda + sa * 8;
    short* dA = lds + tid * 8;
    // B: 1024 chunks (256 rows x 4 slots), 2 per thread
    const int cb0 = tid, cb1 = tid + 512;
    const int rb0 = cb0 >> 2, sb0 = (cb0 & 3) ^ (rb0 & 3);
    const int rb1 = cb1 >> 2, sb1 = (cb1 & 3) ^ (rb1 & 3);
    const short* gB0 = B + (size_t)(n0 + rb0) * ldb + sb0 * 8;
    const short* gB1 = B + (size_t)(n0 + rb1) * ldb + sb1 * 8;
    short* dB0 = lds + 4096 + cb0 * 8;
    short* dB1 = lds + 4096 + cb1 * 8;

    // ds_read offsets (shorts), swizzled: addr = row*32 + (quad ^ (row&3))*8
    int aoff[4], boff[4];
#pragma unroll
    for (int mt = 0; mt < 4; ++mt) {
        int r = wm * 64 + mt * 16 + l15;
        aoff[mt] = r * 32 + ((quad ^ (r & 3)) * 8);
    }
#pragma unroll
    for (int nt = 0; nt < 4; ++nt) {
        int r = wn * 64 + nt * 16 + l15;
        boff[nt] = 4096 + r * 32 + ((quad ^ (r & 3)) * 8);
    }

    const int NT = K >> 5;
#define STAGE_A(t, bb) { gl_lds16(gA + (t) * 32, dA + (bb)); }
#define STAGE_B(t, bb) { gl_lds16(gB0 + (t) * 32, dB0 + (bb)); gl_lds16(gB1 + (t) * 32, dB1 + (bb)); }
    // prologue: tiles 0 and 1 (6 loads/thread in flight)
    STAGE_A(0, 0) STAGE_B(0, 0)
    STAGE_A(1, 12288) STAGE_B(1, 12288)

    for (int kt = 0; kt < NT; ++kt) {
        const int cur = (kt % 3) * 12288;
        const int nxt = ((kt + 2) % 3) * 12288;
        // gate: tile kt landed; tile kt+1 (3 newest loads) stays in flight
        if (kt + 1 < NT) { asm volatile("s_waitcnt vmcnt(3)" ::: "memory"); }
        else             { asm volatile("s_waitcnt vmcnt(0)" ::: "memory"); }
        __builtin_amdgcn_s_barrier();
        __builtin_amdgcn_sched_barrier(0);

        if (kt + 2 < NT) STAGE_A((kt + 2), nxt)

        short8 af[4], bf[4];
#pragma unroll
        for (int mt = 0; mt < 4; ++mt)
            af[mt] = *reinterpret_cast<const short8*>(lds + cur + aoff[mt]);
#pragma unroll
        for (int nt = 0; nt < 2; ++nt)
            bf[nt] = *reinterpret_cast<const short8*>(lds + cur + boff[nt]);
        __builtin_amdgcn_s_setprio(1);
#pragma unroll
        for (int mt = 0; mt < 4; ++mt)
#pragma unroll
            for (int nt = 0; nt < 2; ++nt)
                acc[mt][nt] = __builtin_amdgcn_mfma_f32_16x16x32_bf16(af[mt], bf[nt], acc[mt][nt], 0, 0, 0);
        __builtin_amdgcn_s_setprio(0);

        if (kt + 2 < NT) STAGE_B((kt + 2), nxt)

#pragma unroll
        for (int nt = 2; nt < 4; ++nt)
            bf[nt] = *reinterpret_cast<const short8*>(lds + cur + boff[nt]);
        __builtin_amdgcn_s_setprio(1);
#pragma unroll
        for (int mt = 0; mt < 4; ++mt)
#pragma unroll
            for (int nt = 2; nt < 4; ++nt)
                acc[mt][nt] = __builtin_amdgcn_mfma_f32_16x16x32_bf16(af[mt], bf[nt], acc[mt][nt], 0, 0, 0);
        __builtin_amdgcn_s_setprio(0);
        __builtin_amdgcn_sched_barrier(0);
    }
#undef STAGE_A
#undef STAGE_B
}

// ---------------- fused prep: cast W, zero sums, ctx copy+cast, qh cast+transpose ----------
__global__ __launch_bounds__(256) void prep_kernel(
    const float* __restrict__ ctx, const float* __restrict__ qh,
    const float* __restrict__ Wf, float* __restrict__ out,
    short* __restrict__ W_b, short* __restrict__ ctx_b,
    short* __restrict__ qh_b, short* __restrict__ qhT, float* __restrict__ sums) {
    __shared__ float tile[32][33];
    const int tid = threadIdx.x;
    const int bid = blockIdx.x;
    const int gid = bid * 256 + tid;          // grid = 2048 x 256 = 524288 threads

    // W cast: 147456 float4 items (one pass, gid covers 524288 > 147456)
    if (gid < 147456) {
        float4 v = reinterpret_cast<const float4*>(Wf)[gid];
        short4 o;
        o.x = f2bf(v.x); o.y = f2bf(v.y); o.z = f2bf(v.z); o.w = f2bf(v.w);
        reinterpret_cast<short4*>(W_b)[gid] = o;
    }
    // sums zero: 4096 float4
    if (gid < 4096) {
        float4 z = {0.f, 0.f, 0.f, 0.f};
        reinterpret_cast<float4*>(sums)[gid] = z;
    }
    // ctx: copy into out[:, :, 0:768] and cast to bf16; 3145728 float4 items (6/thread)
#pragma unroll
    for (int it = 0; it < 6; ++it) {
        int i = gid + it * 524288;
        int row = i / 192, c4 = i % 192;
        float4 v = reinterpret_cast<const float4*>(ctx)[i];
        reinterpret_cast<float4*>(out)[(size_t)row * 384 + c4] = v;
        short4 o;
        o.x = f2bf(v.x); o.y = f2bf(v.y); o.z = f2bf(v.z); o.w = f2bf(v.w);
        reinterpret_cast<short4*>(ctx_b)[i] = o;
    }
    // qh: 6144 tiles of 32x32 -> qh_b + qhT; 3 tiles/block
    const int r = tid >> 3, c = (tid & 7) * 4;
#pragma unroll
    for (int it = 0; it < 3; ++it) {
        const int T = bid + it * 2048;
        const int b = T / 768, rem = T % 768;
        const int q0 = (rem / 24) * 32, d0 = (rem % 24) * 32;
        const float4 v = *reinterpret_cast<const float4*>(
            qh + ((size_t)b * LQ + q0 + r) * D + d0 + c);
        tile[r][c] = v.x; tile[r][c + 1] = v.y; tile[r][c + 2] = v.z; tile[r][c + 3] = v.w;
        short4 d;
        d.x = f2bf(v.x); d.y = f2bf(v.y); d.z = f2bf(v.z); d.w = f2bf(v.w);
        *reinterpret_cast<short4*>(qh_b + ((size_t)b * LQ + q0 + r) * D + d0 + c) = d;
        __syncthreads();
        short4 o;
        o.x = f2bf(tile[c][r]); o.y = f2bf(tile[c + 1][r]);
        o.z = f2bf(tile[c + 2][r]); o.w = f2bf(tile[c + 3][r]);
        *reinterpret_cast<short4*>(qhT + ((size_t)b * D + d0 + r) * LQ + q0 + c) = o;
        __syncthreads();
    }
}

// ---------------- GEMM1: query = qh_b * W_b^T + bias -> bf16; 192 blocks (64m x 3n) -------
__global__ __launch_bounds__(512, 4) void gemm1_kernel(
    const short* __restrict__ A, const short* __restrict__ W,
    const float* __restrict__ bias, short* __restrict__ Q) {
    __shared__ __align__(16) short lds[3 * 12288];  // 72 KiB
    const int nb = (blockIdx.x & 7) * 24 + (blockIdx.x >> 3);   // XCD-grouped, 192 = 8*24
    const int m0 = (nb / 3) * 128, n0 = (nb % 3) * 256;
    const int tid = threadIdx.x;
    const int lane = tid & 63, l15 = lane & 15, quad = lane >> 4;
    const int w = tid >> 6, wm = w >> 2, wn = w & 3;
    floatx4 acc[4][4];
#pragma unroll
    for (int i = 0; i < 4; ++i)
#pragma unroll
        for (int j = 0; j < 4; ++j) { floatx4 z = {0.f, 0.f, 0.f, 0.f}; acc[i][j] = z; }
    gemm128x256_loop(A, W, D, D, D, m0, n0, lds, tid, acc);
    float bv[4];
#pragma unroll
    for (int nt = 0; nt < 4; ++nt) bv[nt] = bias[n0 + wn * 64 + nt * 16 + l15];
#pragma unroll
    for (int mt = 0; mt < 4; ++mt)
#pragma unroll
        for (int rr = 0; rr < 4; ++rr) {
            int row = m0 + wm * 64 + mt * 16 + quad * 4 + rr;
#pragma unroll
            for (int nt = 0; nt < 4; ++nt)
                Q[(size_t)row * D + n0 + wn * 64 + nt * 16 + l15] = f2bf(acc[mt][nt][rr] + bv[nt]);
        }
}

// ---------------- K1: P_unnorm + row sums; 512 blocks (8 batch x 16m x 4n) -----------------
__global__ __launch_bounds__(512, 4) void scores_kernel(
    const short* __restrict__ ctxb, const short* __restrict__ query_b,
    const int* __restrict__ qmask, short* __restrict__ P, float* __restrict__ sums) {
    __shared__ __align__(16) short lds[3 * 12288];  // 72 KiB
    const int nb = ((blockIdx.x & 7) << 6) + (blockIdx.x >> 3);  // one batch per XCD, 512 = 8*64
    const int b = nb >> 6, rem = nb & 63, bx = rem >> 2, by = rem & 3;
    const int m0 = bx << 7, n0 = by << 8;
    const int tid = threadIdx.x;
    const int lane = tid & 63, l15 = lane & 15, quad = lane >> 4;
    const int w = tid >> 6, wm = w >> 2, wn = w & 3;
    floatx4 acc[4][4];
#pragma unroll
    for (int i = 0; i < 4; ++i)
#pragma unroll
        for (int j = 0; j < 4; ++j) { floatx4 z = {0.f, 0.f, 0.f, 0.f}; acc[i][j] = z; }
    gemm128x256_loop(ctxb + (size_t)b * LC * D, query_b + (size_t)b * LQ * D,
                     D, D, D, m0, n0, lds, tid, acc);
    const int* mk = qmask + b * LQ;
    bool valid[4];
#pragma unroll
    for (int nt = 0; nt < 4; ++nt) valid[nt] = (mk[n0 + wn * 64 + nt * 16 + l15] != 0);
    short* Pb = P + (size_t)b * LC * LQ;
    float* sumb = sums + (size_t)b * LC;
#pragma unroll
    for (int mt = 0; mt < 4; ++mt)
#pragma unroll
        for (int rr = 0; rr < 4; ++rr) {
            int row = m0 + wm * 64 + mt * 16 + quad * 4 + rr;
            float psum = 0.f;
#pragma unroll
            for (int nt = 0; nt < 4; ++nt) {
                float pv = valid[nt] ? __expf(acc[mt][nt][rr] * SCALE) : 0.f;
                psum += pv;
                Pb[(size_t)row * LQ + n0 + wn * 64 + nt * 16 + l15] = f2bf(pv);
            }
#pragma unroll
            for (int off = 1; off < 16; off <<= 1)
                psum += __shfl_xor(psum, off, 64);
            if (l15 == 0)
                atomicAdd(&sumb[row], psum);
        }
}

// ---------------- K2: attn_out = (P * qhT^T) / rowsum; 384 blocks (8 batch x 16m x 3n) -----
__global__ __launch_bounds__(512, 4) void gemm2_kernel(
    const short* __restrict__ P, const short* __restrict__ qhT,
    const float* __restrict__ sums, float* __restrict__ out) {
    __shared__ __align__(16) short lds[3 * 12288];  // 72 KiB
    const int nb = (blockIdx.x & 7) * 48 + (blockIdx.x >> 3);   // 384 = 8*48
    const int b = nb / 48, rem = nb % 48, bx = rem / 3, by = rem % 3;
    const int m0 = bx << 7, n0 = by << 8;
    const int tid = threadIdx.x;
    const int lane = tid & 63, l15 = lane & 15, quad = lane >> 4;
    const int w = tid >> 6, wm = w >> 2, wn = w & 3;
    floatx4 acc[4][4];
#pragma unroll
    for (int i = 0; i < 4; ++i)
#pragma unroll
        for (int j = 0; j < 4; ++j) { floatx4 z = {0.f, 0.f, 0.f, 0.f}; acc[i][j] = z; }
    gemm128x256_loop(P + (size_t)b * LC * LQ, qhT + (size_t)b * D * LQ,
                     LQ, LQ, LQ, m0, n0, lds, tid, acc);
    const float* sumb = sums + (size_t)b * LC;
#pragma unroll
    for (int mt = 0; mt < 4; ++mt)
#pragma unroll
        for (int rr = 0; rr < 4; ++rr) {
            int lrow = m0 + wm * 64 + mt * 16 + quad * 4 + rr;
            const float inv = 1.0f / sumb[lrow];
            size_t rowoff = ((size_t)b * LC + lrow) * 1536 + 768;
#pragma unroll
            for (int nt = 0; nt < 4; ++nt)
                out[rowoff + n0 + wn * 64 + nt * 16 + l15] = acc[mt][nt][rr] * inv;
        }
}

extern "C" void kernel_launch(void* const* d_in, const int* in_sizes, int n_in,
                              void* d_out, int out_size, void* d_ws, size_t ws_size,
                              hipStream_t stream) {
    const float* ctx = (const float*)d_in[0];
    const float* qh = (const float*)d_in[2];
    const int* qmask = (const int*)d_in[3];
    const float* Wf = (const float*)d_in[4];
    const float* bias = (const float*)d_in[5];
    float* out = (float*)d_out;

    char* ws = (char*)d_ws;
    short* W_b     = (short*)(ws);                  //  1,179,648 B
    short* query_b = (short*)(ws + 1179648);        // 12,582,912 B
    short* qhT     = (short*)(ws + 13762560);       // 12,582,912 B
    short* ctx_b   = (short*)(ws + 26345472);       // 25,165,824 B
    short* P       = (short*)(ws + 51511296);       // 33,554,432 B
    float* sums    = (float*)(ws + 85065728);       //     65,536 B -> end 85,131,264
    short* qh_b    = (short*)(ws + 51511296);       // alias with P (dead before scores writes P)

    prep_kernel<<<2048, 256, 0, stream>>>(ctx, qh, Wf, out, W_b, ctx_b, qh_b, qhT, sums);
    gemm1_kernel<<<192, 512, 0, stream>>>(qh_b, W_b, bias, query_b);
    scores_kernel<<<512, 512, 0, stream>>>(ctx_b, query_b, qmask, P, sums);
    gemm2_kernel<<<384, 512, 0, stream>>>(P, qhT, sums, out);
}